// Round 1
// baseline (611.643 us; speedup 1.0000x reference)
//
#include <hip/hip_runtime.h>

// Problem: B=8, H=W=512, C=32, N_SEGMENTS=256.
// out[b][s][c] = sum_{p: slic[b,p]==s+1} img[b,p,c] / count_{p: slic==s+1, img[b,p,c]!=0}
//
// Strategy: per-block LDS accumulation (padded to kill bank conflicts, counts
// packed 2x16-bit), then one-time atomic flush to a 256 KiB global accumulator
// in d_ws, then a trivial finalize kernel. Memory-bound: 264 MiB read -> ~42us floor.

#define HW_PIX (512 * 512)
#define NSEG 256
#define NCH 32
#define BPI 96           // blocks per image
#define NBLK (8 * BPI)   // 768 total: 3 blocks/CU at 50 KiB LDS each

__global__ __launch_bounds__(256, 3) void seg_avg_main(
    const float* __restrict__ img, const int* __restrict__ slic,
    float* __restrict__ gsum, unsigned* __restrict__ gcnt)
{
    // sums padded to 33 floats/row: bank = (seg*33 + ch) % 32 = (seg + ch) % 32
    __shared__ float    s_sum[NSEG][33];   // 33792 B
    __shared__ unsigned s_cnt[NSEG][17];   // 17408 B (2 channels packed per u32)

    const int tid = threadIdx.x;
    for (int i = tid; i < NSEG * 33; i += 256) (&s_sum[0][0])[i] = 0.0f;
    for (int i = tid; i < NSEG * 17; i += 256) (&s_cnt[0][0])[i] = 0u;
    __syncthreads();

    const int b   = blockIdx.x / BPI;
    const int blk = blockIdx.x % BPI;
    const int sub = tid & 7;    // channel quarter: channels sub*4 .. sub*4+3
    const int pl  = tid >> 3;   // pixel lane within block iteration (0..31)
    const int c0  = sub * 4;

    const float4* __restrict__ imgb =
        (const float4*)(img + (size_t)b * HW_PIX * NCH);
    const int* __restrict__ slicb = slic + (size_t)b * HW_PIX;

    // 32 pixels per block-iteration; stride BPI*32 = 3072 pixels across blocks.
    for (int p = blk * 32 + pl; p < HW_PIX; p += BPI * 32) {
        const int seg = slicb[p] - 1;                 // 0..255
        const float4 v = imgb[(size_t)p * 8 + sub];   // 16 B coalesced

        unsafeAtomicAdd(&s_sum[seg][c0 + 0], v.x);
        unsafeAtomicAdd(&s_sum[seg][c0 + 1], v.y);
        unsafeAtomicAdd(&s_sum[seg][c0 + 2], v.z);
        unsafeAtomicAdd(&s_sum[seg][c0 + 3], v.w);

        const unsigned pk0 = (v.x != 0.0f ? 1u : 0u) | ((v.y != 0.0f ? 1u : 0u) << 16);
        const unsigned pk1 = (v.z != 0.0f ? 1u : 0u) | ((v.w != 0.0f ? 1u : 0u) << 16);
        atomicAdd(&s_cnt[seg][sub * 2 + 0], pk0);
        atomicAdd(&s_cnt[seg][sub * 2 + 1], pk1);
    }
    __syncthreads();

    // Flush block partials to per-image global accumulators (coalesced atomics).
    float*    gs = gsum + (size_t)b * NSEG * NCH;
    unsigned* gc = gcnt + (size_t)b * NSEG * (NCH / 2);
    for (int i = tid; i < NSEG * NCH; i += 256) {
        unsafeAtomicAdd(&gs[i], s_sum[i >> 5][i & 31]);
    }
    for (int i = tid; i < NSEG * (NCH / 2); i += 256) {
        atomicAdd(&gc[i], s_cnt[i >> 4][i & 15]);
    }
}

__global__ __launch_bounds__(256) void seg_avg_final(
    const float* __restrict__ gsum, const unsigned* __restrict__ gcnt,
    float* __restrict__ out)
{
    const int i = blockIdx.x * 256 + threadIdx.x;  // < 8*256*32 = 65536
    const int c  = i & 31;
    const int bs = i >> 5;  // b*256 + seg
    const unsigned packed = gcnt[bs * 16 + (c >> 1)];
    const float cnt = (float)((packed >> ((c & 1) * 16)) & 0xFFFFu);
    out[i] = gsum[i] / cnt;
}

extern "C" void kernel_launch(void* const* d_in, const int* in_sizes, int n_in,
                              void* d_out, int out_size, void* d_ws, size_t ws_size,
                              hipStream_t stream)
{
    const float* img  = (const float*)d_in[0];
    const int*   slic = (const int*)d_in[1];
    float*       out  = (float*)d_out;

    float*    gsum = (float*)d_ws;                                    // 8*256*32 f32 = 128 KiB
    unsigned* gcnt = (unsigned*)((char*)d_ws + 8 * NSEG * NCH * 4);   // 8*256*16 u32 = 128 KiB

    hipMemsetAsync(d_ws, 0, (size_t)(8 * NSEG * NCH * 4 + 8 * NSEG * (NCH / 2) * 4), stream);

    seg_avg_main<<<NBLK, 256, 0, stream>>>(img, slic, gsum, gcnt);
    seg_avg_final<<<(8 * NSEG * NCH) / 256, 256, 0, stream>>>(gsum, gcnt, out);
}

// Round 3
// 605.030 us; speedup vs baseline: 1.0109x; 1.0109x over previous
//
#include <hip/hip_runtime.h>

// B=8, H=W=512, C=32, S=256.
// out[b][s][c] = sum_{p in seg s} img[b,p,c] / #{p in seg s : img[b,p,c] != 0}
//
// R2 theory (resubmitted after GPU-acquisition timeout): R1's 355us was
// LDS-atomic slow path (~139 cyc/atomic instr) — unsafeAtomicAdd on __shared__
// float is NOT ds_add_f32. Fix: plain atomicAdd (native ds_add_f32) + collapse
// 16 count-atomics/pixel into 1 pixel-count atomic with an exact rare-path
// zero correction in global memory.

#define HW_PIX (512 * 512)
#define NSEG 256
#define NCH 32
#define BPI 128          // blocks per image
#define NBLK (8 * BPI)   // 1024 blocks: 4 blocks/CU at ~35 KiB LDS

__global__ __launch_bounds__(256, 4) void seg_avg_main(
    const float* __restrict__ img, const int* __restrict__ slic,
    float* __restrict__ gsum, unsigned* __restrict__ gpix,
    unsigned* __restrict__ gzero)
{
    // pad rows to 33 floats: bank(seg,ch) = (seg + ch) % 32 — all banks reachable
    __shared__ float    s_sum[NSEG][33];   // 33792 B
    __shared__ unsigned s_pix[NSEG];       // 1024 B

    const int tid = threadIdx.x;
    for (int i = tid; i < NSEG * 33; i += 256) (&s_sum[0][0])[i] = 0.0f;
    if (tid < NSEG) s_pix[tid] = 0u;
    __syncthreads();

    const int b   = blockIdx.x / BPI;
    const int blk = blockIdx.x % BPI;
    const int sub = tid & 7;    // channel quad: channels sub*4 .. sub*4+3
    const int pl  = tid >> 3;   // pixel slot (0..31)
    const int c0  = sub * 4;

    const float4* __restrict__ imgb =
        (const float4*)(img + (size_t)b * HW_PIX * NCH);
    const int* __restrict__ slicb = slic + (size_t)b * HW_PIX;

    // 32 pixels/block-iteration; 64 iterations per block.
    for (int p = blk * 32 + pl; p < HW_PIX; p += BPI * 32) {
        const int seg = slicb[p] - 1;                 // 0..255
        const float4 v = imgb[(size_t)p * 8 + sub];   // 16 B, wave reads 1 KiB contiguous

        atomicAdd(&s_sum[seg][c0 + 0], v.x);          // ds_add_f32
        atomicAdd(&s_sum[seg][c0 + 1], v.y);
        atomicAdd(&s_sum[seg][c0 + 2], v.z);
        atomicAdd(&s_sum[seg][c0 + 3], v.w);
        if (sub == 0) atomicAdd(&s_pix[seg], 1u);     // 1 count atomic per pixel

        // Exact nonzero semantics: count values that are exactly 0.0f (rare for
        // random normals) and subtract later. Branch almost never taken.
        const unsigned z = (v.x == 0.0f ? 1u : 0u) | (v.y == 0.0f ? 2u : 0u) |
                           (v.z == 0.0f ? 4u : 0u) | (v.w == 0.0f ? 8u : 0u);
        if (z) {
            unsigned* gz = gzero + ((size_t)(b * NSEG + seg) << 5) + c0;
            if (z & 1u) atomicAdd(gz + 0, 1u);
            if (z & 2u) atomicAdd(gz + 1, 1u);
            if (z & 4u) atomicAdd(gz + 2, 1u);
            if (z & 8u) atomicAdd(gz + 3, 1u);
        }
    }
    __syncthreads();

    // Flush block partials (coalesced, tiny vs hot loop).
    float*    gs = gsum + (size_t)b * NSEG * NCH;
    unsigned* gp = gpix + (size_t)b * NSEG;
    for (int i = tid; i < NSEG * NCH; i += 256)
        unsafeAtomicAdd(&gs[i], s_sum[i >> 5][i & 31]);   // global_atomic_add_f32
    if (tid < NSEG) atomicAdd(&gp[tid], s_pix[tid]);
}

__global__ __launch_bounds__(256) void seg_avg_final(
    const float* __restrict__ gsum, const unsigned* __restrict__ gpix,
    const unsigned* __restrict__ gzero, float* __restrict__ out)
{
    const int i  = blockIdx.x * 256 + threadIdx.x;  // < 65536
    const int bs = i >> 5;                          // b*256 + seg
    const float cnt = (float)(gpix[bs] - gzero[i]);
    out[i] = gsum[i] / cnt;
}

extern "C" void kernel_launch(void* const* d_in, const int* in_sizes, int n_in,
                              void* d_out, int out_size, void* d_ws, size_t ws_size,
                              hipStream_t stream)
{
    const float* img  = (const float*)d_in[0];
    const int*   slic = (const int*)d_in[1];
    float*       out  = (float*)d_out;

    // ws layout: gsum 256 KiB | gpix 8 KiB | gzero 256 KiB
    float*    gsum  = (float*)d_ws;
    unsigned* gpix  = (unsigned*)((char*)d_ws + (size_t)8 * NSEG * NCH * 4);
    unsigned* gzero = (unsigned*)((char*)d_ws + (size_t)8 * NSEG * NCH * 4 + 8 * NSEG * 4);

    const size_t zero_bytes = (size_t)8 * NSEG * NCH * 4 + 8 * NSEG * 4
                            + (size_t)8 * NSEG * NCH * 4;
    hipMemsetAsync(d_ws, 0, zero_bytes, stream);

    seg_avg_main<<<NBLK, 256, 0, stream>>>(img, slic, gsum, gpix, gzero);
    seg_avg_final<<<(8 * NSEG * NCH) / 256, 256, 0, stream>>>(gsum, gpix, gzero, out);
}

// Round 6
// 603.859 us; speedup vs baseline: 1.0129x; 1.0019x over previous
//
#include <hip/hip_runtime.h>

// B=8, H=W=512, C=32, S=256.
// out[b][s][c] = sum_{p in seg s} img[b,p,c] / #{p in seg s : img[b,p,c] != 0}
//
// R3 theory (2nd resubmit after infra failures): R2 proved atomics are NOT
// the bottleneck (10x fewer atomics, same 350us; VALUBusy 1.8%, HBM 6%).
// 820 cyc/wave-iteration == one unhidden load latency -> latency-bound
// dependent chain. Fix: manual 4x unroll with batched independent loads
// (8 VMEM ops in flight/wave) before the LDS scatter.

#define HW_PIX (512 * 512)
#define NSEG 256
#define NCH 32
#define BPI 128          // blocks per image
#define NBLK (8 * BPI)   // 1024 blocks: 4 blocks/CU at ~35 KiB LDS
#define UNROLL 4
#define PSTRIDE (BPI * 32)            // 4096 pixels between unroll slots
#define MSTRIDE (PSTRIDE * UNROLL)    // 16384 pixels between macro-iters
#define MITERS (HW_PIX / MSTRIDE)     // 16, exact — no tail

__global__ __launch_bounds__(256, 4) void seg_avg_main(
    const float* __restrict__ img, const int* __restrict__ slic,
    float* __restrict__ gsum, unsigned* __restrict__ gpix,
    unsigned* __restrict__ gzero)
{
    // pad rows to 33 floats: bank(seg,ch) = (seg + ch) % 32
    __shared__ float    s_sum[NSEG][33];   // 33792 B
    __shared__ unsigned s_pix[NSEG];       // 1024 B

    const int tid = threadIdx.x;
    for (int i = tid; i < NSEG * 33; i += 256) (&s_sum[0][0])[i] = 0.0f;
    if (tid < NSEG) s_pix[tid] = 0u;
    __syncthreads();

    const int b   = blockIdx.x / BPI;
    const int blk = blockIdx.x % BPI;
    const int sub = tid & 7;    // channel quad: channels sub*4 .. sub*4+3
    const int pl  = tid >> 3;   // pixel slot (0..31)
    const int c0  = sub * 4;

    const float4* __restrict__ imgb =
        (const float4*)(img + (size_t)b * HW_PIX * NCH);
    const int* __restrict__ slicb = slic + (size_t)b * HW_PIX;

    const int p0 = blk * 32 + pl;

    for (int it = 0; it < MITERS; ++it) {
        const int pbase = p0 + it * MSTRIDE;

        // ---- load phase: 8 independent VMEM ops, all issued before any use ----
        int    sg[UNROLL];
        float4 vv[UNROLL];
#pragma unroll
        for (int u = 0; u < UNROLL; ++u)
            sg[u] = slicb[pbase + u * PSTRIDE];
#pragma unroll
        for (int u = 0; u < UNROLL; ++u)
            vv[u] = imgb[(size_t)(pbase + u * PSTRIDE) * 8 + sub];

        // ---- consume phase: LDS scatter ----
#pragma unroll
        for (int u = 0; u < UNROLL; ++u) {
            const int seg = sg[u] - 1;                // 0..255
            const float4 v = vv[u];
            atomicAdd(&s_sum[seg][c0 + 0], v.x);      // ds_add_f32
            atomicAdd(&s_sum[seg][c0 + 1], v.y);
            atomicAdd(&s_sum[seg][c0 + 2], v.z);
            atomicAdd(&s_sum[seg][c0 + 3], v.w);
            if (sub == 0) atomicAdd(&s_pix[seg], 1u); // 1 count atomic per pixel

            // Exact nonzero semantics: rare-path correction for exact zeros.
            const unsigned z = (v.x == 0.0f ? 1u : 0u) | (v.y == 0.0f ? 2u : 0u) |
                               (v.z == 0.0f ? 4u : 0u) | (v.w == 0.0f ? 8u : 0u);
            if (z) {
                unsigned* gz = gzero + ((size_t)(b * NSEG + seg) << 5) + c0;
                if (z & 1u) atomicAdd(gz + 0, 1u);
                if (z & 2u) atomicAdd(gz + 1, 1u);
                if (z & 4u) atomicAdd(gz + 2, 1u);
                if (z & 8u) atomicAdd(gz + 3, 1u);
            }
        }
    }
    __syncthreads();

    // Flush block partials (coalesced, tiny vs hot loop).
    float*    gs = gsum + (size_t)b * NSEG * NCH;
    unsigned* gp = gpix + (size_t)b * NSEG;
    for (int i = tid; i < NSEG * NCH; i += 256)
        unsafeAtomicAdd(&gs[i], s_sum[i >> 5][i & 31]);   // global_atomic_add_f32
    if (tid < NSEG) atomicAdd(&gp[tid], s_pix[tid]);
}

__global__ __launch_bounds__(256) void seg_avg_final(
    const float* __restrict__ gsum, const unsigned* __restrict__ gpix,
    const unsigned* __restrict__ gzero, float* __restrict__ out)
{
    const int i  = blockIdx.x * 256 + threadIdx.x;  // < 65536
    const int bs = i >> 5;                          // b*256 + seg
    const float cnt = (float)(gpix[bs] - gzero[i]);
    out[i] = gsum[i] / cnt;
}

extern "C" void kernel_launch(void* const* d_in, const int* in_sizes, int n_in,
                              void* d_out, int out_size, void* d_ws, size_t ws_size,
                              hipStream_t stream)
{
    const float* img  = (const float*)d_in[0];
    const int*   slic = (const int*)d_in[1];
    float*       out  = (float*)d_out;

    // ws layout: gsum 256 KiB | gpix 8 KiB | gzero 256 KiB
    float*    gsum  = (float*)d_ws;
    unsigned* gpix  = (unsigned*)((char*)d_ws + (size_t)8 * NSEG * NCH * 4);
    unsigned* gzero = (unsigned*)((char*)d_ws + (size_t)8 * NSEG * NCH * 4 + 8 * NSEG * 4);

    const size_t zero_bytes = (size_t)8 * NSEG * NCH * 4 + 8 * NSEG * 4
                            + (size_t)8 * NSEG * NCH * 4;
    hipMemsetAsync(d_ws, 0, zero_bytes, stream);

    seg_avg_main<<<NBLK, 256, 0, stream>>>(img, slic, gsum, gpix, gzero);
    seg_avg_final<<<(8 * NSEG * NCH) / 256, 256, 0, stream>>>(gsum, gpix, gzero, out);
}